// Round 1
// baseline (148.250 us; speedup 1.0000x reference)
//
#include <hip/hip_runtime.h>

#define DEVFN static __device__ __forceinline__

constexpr int kB = 2, kL = 1024, kC = 32;
constexpr int kG = 32;               // chunks per chain
constexpr int kCL = kL / kG;         // 32 steps per chunk
constexpr int kNCH = kB * kC;        // 64 chains
constexpr int kNCK = kNCH * kG;      // 2048 chunks
constexpr int kDEPTH = 4;            // prefetch depth in steps
constexpr int kRING = 5;             // LDS ring slots (DEPTH+1: never write slot being read)
constexpr int kSLOT = 576;           // floats per slot: 256 Ar + 256 Ai + 64 X

DEVFN void gload_lds16(const float* g, float* l) {
  __builtin_amdgcn_global_load_lds((const __attribute__((address_space(1))) void*)g,
                                   (__attribute__((address_space(3))) void*)l, 16, 0, 0);
}
DEVFN void gload_lds4(const float* g, float* l) {
  __builtin_amdgcn_global_load_lds((const __attribute__((address_space(1))) void*)g,
                                   (__attribute__((address_space(3))) void*)l, 4, 0, 0);
}

// ---------------- Phase 1: per-chunk transition matrix P_g and response v_g ----------------
// One wave per chunk. Lane (rg = lane>>4, j = lane&15) owns P[4rg+r][j], r=0..3.
// A step tile (2KB) streamed via global_load_lds ring; LDS layout XOR-swizzled on dword bits 2-3
// by row-group (i>>2) so the 4-distinct-address b128 row reads are conflict-free.
__global__ __launch_bounds__(64) void pscan_phase1(
    const float* __restrict__ Ar, const float* __restrict__ Ai,
    const float* __restrict__ Xr, const float* __restrict__ Xi,
    float* __restrict__ Pg, float* __restrict__ Vg) {
  __shared__ __align__(16) float lds[kRING * kSLOT];
  const int lane = threadIdx.x;
  const int j = lane & 15, rg = lane >> 4;
  const int ck = blockIdx.x;
  const int n = ck >> 5, g = ck & 31;       // chain, chunk-in-chain (kG == 32)
  const int b = n >> 5, c = n & 31;
  const int t0 = g * kCL;
  const int perm = lane ^ (lane >> 4);      // inverse swizzle applied to global source (16B units)

  const size_t aBase = ((size_t)(b * kL + t0) * kC + c) * 256;
  const size_t xBase = ((size_t)(b * kL + t0) * kC + c) * 16;
  const size_t aStep = (size_t)kC * 256;
  const size_t xStep = (size_t)kC * 16;
  const float* arG = Ar + aBase + perm * 4;
  const float* aiG = Ai + aBase + perm * 4;
  const float* xG = (lane >= 16 && lane < 32) ? (Xi + xBase + (lane & 15))
                                              : (Xr + xBase + (lane & 15));

  // prologue: fill kDEPTH slots (3 loads per step, constant — vmcnt counting relies on this)
  for (int tt = 0; tt < kDEPTH; ++tt) {
    float* slot = &lds[tt * kSLOT];
    gload_lds16(arG + tt * aStep, slot);
    gload_lds16(aiG + tt * aStep, slot + 256);
    gload_lds4(xG + tt * xStep, slot + 512);
  }

  float pr_[4], pi_[4], wr[4], wi[4];
#pragma unroll
  for (int r = 0; r < 4; ++r) {
    pr_[r] = ((4 * rg + r) == j) ? 1.f : 0.f;   // P = I
    pi_[r] = 0.f; wr[r] = 0.f; wi[r] = 0.f;
  }
  float vjr = 0.f, vji = 0.f;                   // v[j] (own column element)
  const int srcv = ((j >> 2) << 4) | j;         // lane holding row j after butterfly

  for (int tt = 0; tt < kCL; ++tt) {
    // oldest 3 loads (this step) complete; 9 = 3*(kDEPTH-1) newer stay in flight
    asm volatile("s_waitcnt vmcnt(9)" ::: "memory");
    {
      const int ts = (tt + kDEPTH < kCL) ? (tt + kDEPTH) : (kCL - 1);  // dummy re-reads at tail keep count constant
      float* slot = &lds[((tt + kDEPTH) % kRING) * kSLOT];
      gload_lds16(arG + ts * aStep, slot);
      gload_lds16(aiG + ts * aStep, slot + 256);
      gload_lds4(xG + ts * xStep, slot + 512);
    }
    const float* arb = &lds[(tt % kRING) * kSLOT];
    const float* aib = arb + 256;
    const float* xb = arb + 512;

    // ---- fetch P_old column j from the 4 row-groups ----
    float pcr[16], pci[16];
#pragma unroll
    for (int q = 0; q < 4; ++q) {
#pragma unroll
      for (int r = 0; r < 4; ++r) {
        pcr[4 * q + r] = __shfl(pr_[r], 16 * q + j);
        pci[4 * q + r] = __shfl(pi_[r], 16 * q + j);
      }
    }

    // ---- v: partial over k=j, butterfly-reduce over j, add x ----
#pragma unroll
    for (int r = 0; r < 4; ++r) {
      const int off = 64 * rg + 16 * r + (j ^ (rg << 2));   // swizzled A[4rg+r][j]
      const float avr = arb[off], avi = aib[off];
      wr[r] = avr * vjr - avi * vji;
      wi[r] = avr * vji + avi * vjr;
    }
#pragma unroll
    for (int m = 1; m <= 8; m <<= 1) {
#pragma unroll
      for (int r = 0; r < 4; ++r) {
        wr[r] += __shfl_xor(wr[r], m);
        wi[r] += __shfl_xor(wi[r], m);
      }
    }
#pragma unroll
    for (int r = 0; r < 4; ++r) {
      wr[r] += xb[4 * rg + r];
      wi[r] += xb[16 + 4 * rg + r];
    }
    {
      const int m0 = j & 3;   // export own row (j&3), fetch v_new[j] from lane (j>>2, j)
      const float er = (m0 & 2) ? ((m0 & 1) ? wr[3] : wr[2]) : ((m0 & 1) ? wr[1] : wr[0]);
      const float ei = (m0 & 2) ? ((m0 & 1) ? wi[3] : wi[2]) : ((m0 & 1) ? wi[1] : wi[0]);
      vjr = __shfl(er, srcv);
      vji = __shfl(ei, srcv);
    }

    // ---- P update: P_new[4rg+r][j] = sum_k A[4rg+r][k] * pcol[k] ----
    float npr[4] = {0.f, 0.f, 0.f, 0.f}, npi[4] = {0.f, 0.f, 0.f, 0.f};
#pragma unroll
    for (int kc = 0; kc < 4; ++kc) {
      float4 a4r[4], a4i[4];
#pragma unroll
      for (int r = 0; r < 4; ++r) {
        const int off = 64 * rg + 16 * r + 4 * (kc ^ rg);   // swizzled A[4rg+r][4kc..4kc+3]
        a4r[r] = *(const float4*)(arb + off);
        a4i[r] = *(const float4*)(aib + off);
      }
#pragma unroll
      for (int r = 0; r < 4; ++r) {
        const float* fr = (const float*)&a4r[r];
        const float* fi = (const float*)&a4i[r];
#pragma unroll
        for (int mm = 0; mm < 4; ++mm) {
          const int k = 4 * kc + mm;
          npr[r] += fr[mm] * pcr[k] - fi[mm] * pci[k];
          npi[r] += fr[mm] * pci[k] + fi[mm] * pcr[k];
        }
      }
    }
#pragma unroll
    for (int r = 0; r < 4; ++r) { pr_[r] = npr[r]; pi_[r] = npi[r]; }
  }

  // ---- store P_g (interleaved complex [i][j]) and v_g ----
  float* pgb = Pg + (size_t)ck * 512;
#pragma unroll
  for (int r = 0; r < 4; ++r) {
    float2 v; v.x = pr_[r]; v.y = pi_[r];
    *(float2*)(pgb + ((4 * rg + r) * 16 + j) * 2) = v;
  }
  if (j == 0) {
#pragma unroll
    for (int r = 0; r < 4; ++r) {
      float2 v; v.x = wr[r]; v.y = wi[r];
      *(float2*)(Vg + (size_t)ck * 32 + (4 * rg + r) * 2) = v;
    }
  }
}

// ---------------- Phase 2: sequential carry scan over chunks (one wave per chain) ----------------
// Stores S_{g-1} (state BEFORE chunk g) to Sg[chain*kG+g]; S_{-1} = 0.
__global__ __launch_bounds__(64) void pscan_phase2(
    const float* __restrict__ Pg, const float* __restrict__ Vg, float* __restrict__ Sg) {
  const int lane = threadIdx.x;
  const int j = lane & 15, rg = lane >> 4;
  const int n = blockIdx.x;
  const int srcv = ((j >> 2) << 4) | j;
  float yjr = 0.f, yji = 0.f;
  for (int g = 0; g < kG; ++g) {
    const size_t ck = (size_t)n * kG + g;
    if (rg == 0) {
      float2 s; s.x = yjr; s.y = yji;
      *(float2*)(Sg + ck * 32 + j * 2) = s;
    }
    float wr[4], wi[4];
#pragma unroll
    for (int r = 0; r < 4; ++r) {
      const float2 p = *(const float2*)(Pg + ck * 512 + ((4 * rg + r) * 16 + j) * 2);
      wr[r] = p.x * yjr - p.y * yji;
      wi[r] = p.x * yji + p.y * yjr;
    }
#pragma unroll
    for (int m = 1; m <= 8; m <<= 1) {
#pragma unroll
      for (int r = 0; r < 4; ++r) {
        wr[r] += __shfl_xor(wr[r], m);
        wi[r] += __shfl_xor(wi[r], m);
      }
    }
    const float4 v0 = *(const float4*)(Vg + ck * 32 + rg * 8);
    const float4 v1 = *(const float4*)(Vg + ck * 32 + rg * 8 + 4);
    wr[0] += v0.x; wi[0] += v0.y; wr[1] += v0.z; wi[1] += v0.w;
    wr[2] += v1.x; wi[2] += v1.y; wr[3] += v1.z; wi[3] += v1.w;
    const int m0 = j & 3;
    const float er = (m0 & 2) ? ((m0 & 1) ? wr[3] : wr[2]) : ((m0 & 1) ? wr[1] : wr[0]);
    const float ei = (m0 & 2) ? ((m0 & 1) ? wi[3] : wi[2]) : ((m0 & 1) ? wi[1] : wi[0]);
    yjr = __shfl(er, srcv);
    yji = __shfl(ei, srcv);
  }
}

// ---------------- Phase 3: replay chunk from its carry state, write Y ----------------
// Matvec consumes each A element exactly once -> plain register loads, double-buffered.
__global__ __launch_bounds__(64) void pscan_phase3(
    const float* __restrict__ Ar, const float* __restrict__ Ai,
    const float* __restrict__ Xr, const float* __restrict__ Xi,
    const float* __restrict__ Sg, float* __restrict__ out) {
  const int lane = threadIdx.x;
  const int j = lane & 15, rg = lane >> 4;
  const int ck = blockIdx.x;
  const int n = ck >> 5, g = ck & 31;
  const int b = n >> 5, c = n & 31;
  const int t0 = g * kCL;
  const int srcv = ((j >> 2) << 4) | j;

  const size_t aBase = ((size_t)(b * kL + t0) * kC + c) * 256;
  const size_t xBase = ((size_t)(b * kL + t0) * kC + c) * 16;
  const size_t aStep = (size_t)kC * 256;
  const size_t xStep = (size_t)kC * 16;
  const float* arB = Ar + aBase + 64 * rg + j;
  const float* aiB = Ai + aBase + 64 * rg + j;
  const float* xrB = Xr + xBase + 4 * rg;
  const float* xiB = Xi + xBase + 4 * rg;
  float* outB = out + ((size_t)(b * kL + t0) * kC + c) * 32;

  const float2 s0 = *(const float2*)(Sg + (size_t)ck * 32 + j * 2);
  float yjr = s0.x, yji = s0.y;

  float car[4], cai[4];
  float4 cxr, cxi;
#pragma unroll
  for (int r = 0; r < 4; ++r) { car[r] = arB[16 * r]; cai[r] = aiB[16 * r]; }
  cxr = *(const float4*)(xrB);
  cxi = *(const float4*)(xiB);

  for (int tt = 0; tt < kCL; ++tt) {
    float nar[4] = {0.f, 0.f, 0.f, 0.f}, nai[4] = {0.f, 0.f, 0.f, 0.f};
    float4 nxr = cxr, nxi = cxi;
    const bool more = (tt + 1 < kCL);
    if (more) {
      const float* a1 = arB + (size_t)(tt + 1) * aStep;
      const float* a2 = aiB + (size_t)(tt + 1) * aStep;
#pragma unroll
      for (int r = 0; r < 4; ++r) { nar[r] = a1[16 * r]; nai[r] = a2[16 * r]; }
      nxr = *(const float4*)(xrB + (size_t)(tt + 1) * xStep);
      nxi = *(const float4*)(xiB + (size_t)(tt + 1) * xStep);
    }
    float wr[4], wi[4];
#pragma unroll
    for (int r = 0; r < 4; ++r) {
      wr[r] = car[r] * yjr - cai[r] * yji;
      wi[r] = car[r] * yji + cai[r] * yjr;
    }
#pragma unroll
    for (int m = 1; m <= 8; m <<= 1) {
#pragma unroll
      for (int r = 0; r < 4; ++r) {
        wr[r] += __shfl_xor(wr[r], m);
        wi[r] += __shfl_xor(wi[r], m);
      }
    }
    const float* xr4 = (const float*)&cxr;
    const float* xi4 = (const float*)&cxi;
#pragma unroll
    for (int r = 0; r < 4; ++r) { wr[r] += xr4[r]; wi[r] += xi4[r]; }
    const int m0 = j & 3;
    const float er = (m0 & 2) ? ((m0 & 1) ? wr[3] : wr[2]) : ((m0 & 1) ? wr[1] : wr[0]);
    const float ei = (m0 & 2) ? ((m0 & 1) ? wi[3] : wi[2]) : ((m0 & 1) ? wi[1] : wi[0]);
    yjr = __shfl(er, srcv);
    yji = __shfl(ei, srcv);
    if (rg == 0) {
      float2 o; o.x = yjr; o.y = yji;
      *(float2*)(outB + (size_t)tt * (kC * 32) + j * 2) = o;   // 128B coalesced per step
    }
#pragma unroll
    for (int r = 0; r < 4; ++r) { car[r] = nar[r]; cai[r] = nai[r]; }
    cxr = nxr; cxi = nxi;
  }
}

extern "C" void kernel_launch(void* const* d_in, const int* in_sizes, int n_in,
                              void* d_out, int out_size, void* d_ws, size_t ws_size,
                              hipStream_t stream) {
  const float* Ar = (const float*)d_in[0];
  const float* Ai = (const float*)d_in[1];
  const float* Xr = (const float*)d_in[2];
  const float* Xi = (const float*)d_in[3];
  // Workspace: Pg 4MB + Vg 256KB + Sg 256KB = 4.5 MB
  float* Pg = (float*)d_ws;
  float* Vg = Pg + (size_t)kNCK * 512;
  float* Sg = Vg + (size_t)kNCK * 32;

  pscan_phase1<<<kNCK, 64, 0, stream>>>(Ar, Ai, Xr, Xi, Pg, Vg);
  pscan_phase2<<<kNCH, 64, 0, stream>>>(Pg, Vg, Sg);
  pscan_phase3<<<kNCK, 64, 0, stream>>>(Ar, Ai, Xr, Xi, Sg, (float*)d_out);
}